// Round 2
// baseline (451.723 us; speedup 1.0000x reference)
//
#include <hip/hip_runtime.h>
#include <hip/hip_bf16.h>

#define TSTEPS 365
#define BGRID  20000
#define NMUL   4
#define NEARZERO 1e-6f

// --- dtype sniffer -----------------------------------------------------------
// If forcing is bf16: uint16 slots 0,6,12,... are prcp values in [0, 10.5].
// If forcing is fp32: those slots are low mantissa halves -> random bits.
// P(64 random samples all look like nonneg bf16 <= 16) ~ 0.26^64 ~= 1e-38.
__global__ void detect_dtype(const unsigned short* __restrict__ f,
                             int* __restrict__ flag) {
    if (blockIdx.x == 0 && threadIdx.x == 0) {
        int ok = 1;
        for (int k = 0; k < 64; ++k) {
            unsigned int bits = f[k * 6];
            float v = __uint_as_float(bits << 16);   // bf16 -> fp32 is exact
            if (!(v >= 0.0f && v <= 16.0f)) ok = 0;  // NaN fails this too
        }
        *flag = ok;  // 1 => bf16, 0 => fp32
    }
}

template<int IS_BF16>
__device__ __forceinline__ float ld(const void* p, int i) {
    if (IS_BF16) {
        unsigned int b = ((const unsigned short*)p)[i];
        return __uint_as_float(b << 16);
    } else {
        return ((const float*)p)[i];
    }
}

template<int IS_BF16>
__device__ __forceinline__ void st(void* p, int i, float v) {
    if (IS_BF16) {
        ((__hip_bfloat16*)p)[i] = __float2bfloat16(v);
    } else {
        ((float*)p)[i] = v;
    }
}

// thread = b*NMUL + k  (b = basin, k = nmul component)
// out layout: [ Qsim_avg (T,B) | Qsim (T,B,NMUL) ]
template<int IS_BF16>
__global__ __launch_bounds__(256) void hbv_fwd(
    const int* __restrict__ flag,
    const void* __restrict__ forcing,   // (T, B, 3)
    const void* __restrict__ pBETA, const void* __restrict__ pFC,
    const void* __restrict__ pK0,   const void* __restrict__ pK1,
    const void* __restrict__ pK2,   const void* __restrict__ pLP,
    const void* __restrict__ pPERC, const void* __restrict__ pUZL,
    const void* __restrict__ pTT,   const void* __restrict__ pCFMAX,
    const void* __restrict__ pCFR,  const void* __restrict__ pCWH,
    const void* __restrict__ pBETAET, const void* __restrict__ pC,
    void* __restrict__ out_avg,         // (T, B)
    void* __restrict__ out_q)           // (T, B, NMUL)
{
    if (*flag != IS_BF16) return;       // wrong-dtype variant: no-op

    const int tid = blockIdx.x * blockDim.x + threadIdx.x;
    if (tid >= BGRID * NMUL) return;
    const int b = tid >> 2;
    const int k = tid & 3;

    const float parBETA   = ld<IS_BF16>(pBETA, tid);
    const float parFC     = ld<IS_BF16>(pFC, tid);
    const float parK0     = ld<IS_BF16>(pK0, tid);
    const float parK1     = ld<IS_BF16>(pK1, tid);
    const float parK2     = ld<IS_BF16>(pK2, tid);
    const float parLP     = ld<IS_BF16>(pLP, tid);
    const float parPERC   = ld<IS_BF16>(pPERC, tid);
    const float parUZL    = ld<IS_BF16>(pUZL, tid);
    const float parTT     = ld<IS_BF16>(pTT, tid);
    const float parCFMAX  = ld<IS_BF16>(pCFMAX, tid);
    const float parCFR    = ld<IS_BF16>(pCFR, tid);
    const float parCWH    = ld<IS_BF16>(pCWH, tid);
    const float parBETAET = ld<IS_BF16>(pBETAET, tid);
    const float parC      = ld<IS_BF16>(pC, tid);

    const float refreeze_coef = parCFR * parCFMAX;
    const float inv_FC   = 1.0f / parFC;
    const float inv_LPFC = 1.0f / (parLP * parFC);

    float snow = NEARZERO, melt = 0.0f, sm = 0.0f, suz = 0.0f, slz = 0.0f;

    int fidx = b * 3;
    int qaidx = b;
    int qqidx = tid;

    for (int t = 0; t < TSTEPS; ++t) {
        const float p   = ld<IS_BF16>(forcing, fidx + 0);
        const float tv  = ld<IS_BF16>(forcing, fidx + 1);
        const float pet = ld<IS_BF16>(forcing, fidx + 2);
        fidx += BGRID * 3;

        // snow module
        const float temp_diff = tv - parTT;
        const bool  is_rain = temp_diff > 0.0f;
        const float rain       = is_rain ? p : 0.0f;
        const float snow_input = is_rain ? 0.0f : p;
        float snow1 = snow + snow_input;
        const float pot_melt = parCFMAX * fmaxf(temp_diff, 0.0f);
        const float melt_amount = fminf(pot_melt, snow1);
        snow1 -= melt_amount;
        float melt1 = melt + melt_amount;
        const float pot_refreeze = refreeze_coef * fmaxf(-temp_diff, 0.0f);
        const float refreeze = fminf(pot_refreeze, melt1);
        snow = snow1 + refreeze;
        melt1 -= refreeze;
        const float tosoil = fmaxf(melt1 - parCWH * snow, 0.0f);
        melt = melt1 - tosoil;

        // soil module
        const float x1 = fmaxf(sm * inv_FC, NEARZERO);
        const float soil_wet = fminf(fmaxf(__builtin_exp2f(parBETA * __log2f(x1)), 0.0f), 1.0f);
        const float rt = rain + tosoil;
        const float recharge = rt * soil_wet;
        float sm1 = sm + rt - recharge;
        const float excess = fmaxf(sm1 - parFC, 0.0f);
        sm1 -= excess;
        const float ef1 = fminf(fmaxf(sm1 * inv_LPFC, 0.0f), 1.0f);
        const float x2 = fmaxf(ef1, NEARZERO);
        const float evapfactor = fminf(fmaxf(__builtin_exp2f(parBETAET * __log2f(x2)), 0.0f), 1.0f);
        const float etact = fminf(pet * evapfactor, sm1);
        const float sm_ae = fmaxf(sm1 - etact, NEARZERO);
        const float sm_ratio = fminf(sm_ae * inv_FC, 1.0f);
        const float capillary = fminf(slz, parC * slz * (1.0f - sm_ratio));
        sm = fmaxf(sm_ae + capillary, NEARZERO);
        float slz1 = fmaxf(slz - capillary, NEARZERO);

        // response routine
        float suz1 = suz + recharge + excess;
        const float perc_flux = fminf(suz1, parPERC);
        suz1 -= perc_flux;
        slz1 += perc_flux;
        const float q0 = parK0 * fmaxf(suz1 - parUZL, 0.0f);
        suz1 -= q0;
        const float q1 = parK1 * suz1;
        suz = suz1 - q1;
        const float q2 = parK2 * slz1;
        slz = slz1 - q2;
        const float q = q0 + q1 + q2;

        st<IS_BF16>(out_q, qqidx, q);
        qqidx += BGRID * NMUL;
        float qs = q + __shfl_xor(q, 1, 64);
        qs += __shfl_xor(qs, 2, 64);
        if (k == 0) st<IS_BF16>(out_avg, qaidx, qs * 0.25f);
        qaidx += BGRID;
    }
}

extern "C" void kernel_launch(void* const* d_in, const int* in_sizes, int n_in,
                              void* d_out, int out_size, void* d_ws, size_t ws_size,
                              hipStream_t stream) {
    // setup_inputs() dict order:
    // 0 forcing, 1 parBETA, 2 parFC, 3 parK0, 4 parK1, 5 parK2, 6 parLP,
    // 7 parPERC, 8 parUZL, 9 parTT, 10 parCFMAX, 11 parCFR, 12 parCWH,
    // 13 parBETAET, 14 parC
    int* flag = (int*)d_ws;
    detect_dtype<<<1, 64, 0, stream>>>((const unsigned short*)d_in[0], flag);

    // out layout: avg (T*B) then q (T*B*NMUL), elements of the real dtype
    char* out_base = (char*)d_out;
    const int total = BGRID * NMUL;  // 80000
    const int block = 256;
    const int grid  = (total + block - 1) / block;  // 313

    // bf16 variant
    {
        void* out_avg = out_base;
        void* out_q   = out_base + (size_t)TSTEPS * BGRID * sizeof(__hip_bfloat16);
        hbv_fwd<1><<<grid, block, 0, stream>>>(flag, d_in[0],
            d_in[1], d_in[2], d_in[3], d_in[4], d_in[5], d_in[6], d_in[7],
            d_in[8], d_in[9], d_in[10], d_in[11], d_in[12], d_in[13], d_in[14],
            out_avg, out_q);
    }
    // fp32 variant
    {
        void* out_avg = out_base;
        void* out_q   = out_base + (size_t)TSTEPS * BGRID * sizeof(float);
        hbv_fwd<0><<<grid, block, 0, stream>>>(flag, d_in[0],
            d_in[1], d_in[2], d_in[3], d_in[4], d_in[5], d_in[6], d_in[7],
            d_in[8], d_in[9], d_in[10], d_in[11], d_in[12], d_in[13], d_in[14],
            out_avg, out_q);
    }
}

// Round 3
// 320.754 us; speedup vs baseline: 1.4083x; 1.4083x over previous
//
#include <hip/hip_runtime.h>

#define TSTEPS 365
#define BGRID  20000
#define NMUL   4
#define NEARZERO 1e-6f
#define PF 16           // prefetch depth (iterations of forcing held in registers)

struct F3 { float p, t, pet; };   // 12B, matches (.., 3) innermost layout

// thread = b*NMUL + k.  out layout: [ Qsim_avg (T,B) | Qsim (T,B,NMUL) ]  fp32
__global__ __launch_bounds__(64) void hbv_fwd(
    const float* __restrict__ forcing,   // (T, B, 3)
    const float* __restrict__ pBETA,  const float* __restrict__ pFC,
    const float* __restrict__ pK0,    const float* __restrict__ pK1,
    const float* __restrict__ pK2,    const float* __restrict__ pLP,
    const float* __restrict__ pPERC,  const float* __restrict__ pUZL,
    const float* __restrict__ pTT,    const float* __restrict__ pCFMAX,
    const float* __restrict__ pCFR,   const float* __restrict__ pCWH,
    const float* __restrict__ pBETAET,const float* __restrict__ pC,
    float* __restrict__ out_avg,         // (T, B)
    float* __restrict__ out_q)           // (T, B, NMUL)
{
    const int tid = blockIdx.x * 64 + threadIdx.x;
    if (tid >= BGRID * NMUL) return;
    const int b = tid >> 2;
    const int k = tid & 3;

    const float parBETA   = pBETA[tid];
    const float parFC     = pFC[tid];
    const float parK0     = pK0[tid];
    const float parK1     = pK1[tid];
    const float parK2     = pK2[tid];
    const float parLP     = pLP[tid];
    const float parPERC   = pPERC[tid];
    const float parUZL    = pUZL[tid];
    const float parTT     = pTT[tid];
    const float parCFMAX  = pCFMAX[tid];
    const float parCFR    = pCFR[tid];
    const float parCWH    = pCWH[tid];
    const float parBETAET = pBETAET[tid];
    const float parC      = pC[tid];

    const float refreeze_coef = parCFR * parCFMAX;
    const float inv_FC   = 1.0f / parFC;
    const float inv_LPFC = 1.0f / (parLP * parFC);

    float snow = NEARZERO, melt = 0.0f, sm = 0.0f, suz = 0.0f, slz = 0.0f;

    const F3* __restrict__ f3 = (const F3*)forcing;  // index: t*BGRID + b

    // --- prefetch ring: PF iterations of forcing in registers -------------
    F3 buf[PF];
#pragma unroll
    for (int i = 0; i < PF; ++i) buf[i] = f3[i * BGRID + b];

    auto step = [&](const F3 fv, const int t) {
        const float p   = fv.p;
        const float tv  = fv.t;
        const float pet = fv.pet;

        // snow module
        const float temp_diff = tv - parTT;
        const bool  is_rain = temp_diff > 0.0f;
        const float rain       = is_rain ? p : 0.0f;
        const float snow_input = is_rain ? 0.0f : p;
        float snow1 = snow + snow_input;
        const float pot_melt = parCFMAX * fmaxf(temp_diff, 0.0f);
        const float melt_amount = fminf(pot_melt, snow1);
        snow1 -= melt_amount;
        float melt1 = melt + melt_amount;
        const float pot_refreeze = refreeze_coef * fmaxf(-temp_diff, 0.0f);
        const float refreeze = fminf(pot_refreeze, melt1);
        snow = snow1 + refreeze;
        melt1 -= refreeze;
        const float tosoil = fmaxf(melt1 - parCWH * snow, 0.0f);
        melt = melt1 - tosoil;

        // soil module
        const float x1 = fmaxf(sm * inv_FC, NEARZERO);
        const float soil_wet = fminf(fmaxf(__builtin_exp2f(parBETA * __log2f(x1)), 0.0f), 1.0f);
        const float rt = rain + tosoil;
        const float recharge = rt * soil_wet;
        float sm1 = sm + rt - recharge;
        const float excess = fmaxf(sm1 - parFC, 0.0f);
        sm1 -= excess;
        const float ef1 = fminf(fmaxf(sm1 * inv_LPFC, 0.0f), 1.0f);
        const float x2 = fmaxf(ef1, NEARZERO);
        const float evapfactor = fminf(fmaxf(__builtin_exp2f(parBETAET * __log2f(x2)), 0.0f), 1.0f);
        const float etact = fminf(pet * evapfactor, sm1);
        const float sm_ae = fmaxf(sm1 - etact, NEARZERO);
        const float sm_ratio = fminf(sm_ae * inv_FC, 1.0f);
        const float capillary = fminf(slz, parC * slz * (1.0f - sm_ratio));
        sm = fmaxf(sm_ae + capillary, NEARZERO);
        float slz1 = fmaxf(slz - capillary, NEARZERO);

        // response routine
        float suz1 = suz + recharge + excess;
        const float perc_flux = fminf(suz1, parPERC);
        suz1 -= perc_flux;
        slz1 += perc_flux;
        const float q0 = parK0 * fmaxf(suz1 - parUZL, 0.0f);
        suz1 -= q0;
        const float q1 = parK1 * suz1;
        suz = suz1 - q1;
        const float q2 = parK2 * slz1;
        slz = slz1 - q2;
        const float q = q0 + q1 + q2;

        out_q[(size_t)t * (BGRID * NMUL) + tid] = q;
        float qs = q + __shfl_xor(q, 1, 64);
        qs += __shfl_xor(qs, 2, 64);
        if (k == 0) out_avg[(size_t)t * BGRID + b] = qs * 0.25f;
    };

    constexpr int MAIN = (TSTEPS / PF) * PF;  // 352
    for (int base = 0; base < MAIN; base += PF) {
#pragma unroll
        for (int j = 0; j < PF; ++j) {
            const F3 fv = buf[j];
            const int tp = base + j + PF;
            if (tp < TSTEPS) buf[j] = f3[tp * BGRID + b];  // refill ring
            step(fv, base + j);
        }
    }
#pragma unroll
    for (int j = 0; j < TSTEPS - MAIN; ++j) {  // tail: 13 steps, already in ring
        step(buf[j], MAIN + j);
    }
}

extern "C" void kernel_launch(void* const* d_in, const int* in_sizes, int n_in,
                              void* d_out, int out_size, void* d_ws, size_t ws_size,
                              hipStream_t stream) {
    // inputs (fp32, confirmed via WRITE_SIZE == T*B*5*4 B):
    // 0 forcing, 1 parBETA, 2 parFC, 3 parK0, 4 parK1, 5 parK2, 6 parLP,
    // 7 parPERC, 8 parUZL, 9 parTT, 10 parCFMAX, 11 parCFR, 12 parCWH,
    // 13 parBETAET, 14 parC
    const float* forcing = (const float*)d_in[0];

    float* out_avg = (float*)d_out;                          // (T, B)
    float* out_q   = out_avg + (size_t)TSTEPS * BGRID;       // (T, B, NMUL)

    const int total = BGRID * NMUL;    // 80000
    const int block = 64;              // 1250 single-wave workgroups -> even CU spread
    const int grid  = (total + block - 1) / block;
    hbv_fwd<<<grid, block, 0, stream>>>(forcing,
        (const float*)d_in[1], (const float*)d_in[2], (const float*)d_in[3],
        (const float*)d_in[4], (const float*)d_in[5], (const float*)d_in[6],
        (const float*)d_in[7], (const float*)d_in[8], (const float*)d_in[9],
        (const float*)d_in[10], (const float*)d_in[11], (const float*)d_in[12],
        (const float*)d_in[13], (const float*)d_in[14],
        out_avg, out_q);
}

// Round 4
// 303.601 us; speedup vs baseline: 1.4879x; 1.0565x over previous
//
#include <hip/hip_runtime.h>

#define TSTEPS 365
#define BGRID  20000
#define NMUL   4
#define NEARZERO 1e-6f
#define PF 8            // prefetch ring depth (iterations of forcing in registers)

struct F3 { float p, t, pet; };   // 12B, innermost (.,3) layout

// thread = b*NMUL + k.  out layout: [ Qsim_avg (T,B) | Qsim (T,B,NMUL) ]  fp32
// __launch_bounds__(64,2): min 2 waves/EU -> VGPR cap 256. Grid supplies only
// ~1.22 waves/SIMD, so capping at 2 costs nothing and frees registers for the
// prefetch ring (round 3: default cap of 64 VGPRs defeated the ring).
__global__ __launch_bounds__(64, 2) void hbv_fwd(
    const float* __restrict__ forcing,   // (T, B, 3)
    const float* __restrict__ pBETA,  const float* __restrict__ pFC,
    const float* __restrict__ pK0,    const float* __restrict__ pK1,
    const float* __restrict__ pK2,    const float* __restrict__ pLP,
    const float* __restrict__ pPERC,  const float* __restrict__ pUZL,
    const float* __restrict__ pTT,    const float* __restrict__ pCFMAX,
    const float* __restrict__ pCFR,   const float* __restrict__ pCWH,
    const float* __restrict__ pBETAET,const float* __restrict__ pC,
    float* __restrict__ out_avg,         // (T, B)
    float* __restrict__ out_q)           // (T, B, NMUL)
{
    const int tid = blockIdx.x * 64 + threadIdx.x;
    if (tid >= BGRID * NMUL) return;
    const int b = tid >> 2;
    const int k = tid & 3;

    const float parBETA   = pBETA[tid];
    const float parFC     = pFC[tid];
    const float parK0     = pK0[tid];
    const float parK1     = pK1[tid];
    const float parK2     = pK2[tid];
    const float parLP     = pLP[tid];
    const float parPERC   = pPERC[tid];
    const float parUZL    = pUZL[tid];
    const float parTT     = pTT[tid];
    const float parCFMAX  = pCFMAX[tid];
    const float parCFR    = pCFR[tid];
    const float parCWH    = pCWH[tid];
    const float parBETAET = pBETAET[tid];
    const float parC      = pC[tid];

    const float refreeze_coef = parCFR * parCFMAX;
    const float inv_FC   = 1.0f / parFC;
    const float inv_LPFC = 1.0f / (parLP * parFC);

    float snow = NEARZERO, melt = 0.0f, sm = 0.0f, suz = 0.0f, slz = 0.0f;

    const F3* __restrict__ f3 = (const F3*)forcing;

    // running 32-bit element offsets (saddr + voffset addressing, no per-step mul)
    unsigned fofs  = (unsigned)b;            // into f3, stride BGRID per t
    unsigned qqofs = (unsigned)tid;          // into out_q, stride BGRID*NMUL
    unsigned qaofs = (unsigned)b;            // into out_avg, stride BGRID

    // --- fill prefetch ring ------------------------------------------------
    F3 buf[PF];
#pragma unroll
    for (int i = 0; i < PF; ++i) { buf[i] = f3[fofs]; fofs += BGRID; }
    // fofs now points at t = PF

    auto step = [&](const F3 fv) {
        const float p   = fv.p;
        const float tv  = fv.t;
        const float pet = fv.pet;

        // snow module
        const float temp_diff = tv - parTT;
        const bool  is_rain = temp_diff > 0.0f;
        const float rain       = is_rain ? p : 0.0f;
        const float snow_input = is_rain ? 0.0f : p;
        float snow1 = snow + snow_input;
        const float pot_melt = parCFMAX * fmaxf(temp_diff, 0.0f);
        const float melt_amount = fminf(pot_melt, snow1);
        snow1 -= melt_amount;
        float melt1 = melt + melt_amount;
        const float pot_refreeze = refreeze_coef * fmaxf(-temp_diff, 0.0f);
        const float refreeze = fminf(pot_refreeze, melt1);
        snow = snow1 + refreeze;
        melt1 -= refreeze;
        const float tosoil = fmaxf(melt1 - parCWH * snow, 0.0f);
        melt = melt1 - tosoil;

        // soil module
        const float x1 = fmaxf(sm * inv_FC, NEARZERO);
        const float soil_wet = fminf(fmaxf(__builtin_exp2f(parBETA * __log2f(x1)), 0.0f), 1.0f);
        const float rt = rain + tosoil;
        const float recharge = rt * soil_wet;
        float sm1 = sm + rt - recharge;
        const float excess = fmaxf(sm1 - parFC, 0.0f);
        sm1 -= excess;
        const float ef1 = fminf(fmaxf(sm1 * inv_LPFC, 0.0f), 1.0f);
        const float x2 = fmaxf(ef1, NEARZERO);
        const float evapfactor = fminf(fmaxf(__builtin_exp2f(parBETAET * __log2f(x2)), 0.0f), 1.0f);
        const float etact = fminf(pet * evapfactor, sm1);
        const float sm_ae = fmaxf(sm1 - etact, NEARZERO);
        const float sm_ratio = fminf(sm_ae * inv_FC, 1.0f);
        const float capillary = fminf(slz, parC * slz * (1.0f - sm_ratio));
        sm = fmaxf(sm_ae + capillary, NEARZERO);
        float slz1 = fmaxf(slz - capillary, NEARZERO);

        // response routine
        float suz1 = suz + recharge + excess;
        const float perc_flux = fminf(suz1, parPERC);
        suz1 -= perc_flux;
        slz1 += perc_flux;
        const float q0 = parK0 * fmaxf(suz1 - parUZL, 0.0f);
        suz1 -= q0;
        const float q1 = parK1 * suz1;
        suz = suz1 - q1;
        const float q2 = parK2 * slz1;
        slz = slz1 - q2;
        const float q = q0 + q1 + q2;

        out_q[qqofs] = q;
        qqofs += BGRID * NMUL;
        float qs = q + __shfl_xor(q, 1, 64);
        qs += __shfl_xor(qs, 2, 64);
        if (k == 0) out_avg[qaofs] = qs * 0.25f;
        qaofs += BGRID;
    };

    // --- main: 44 full chunks of PF=8, prefetch always in range (no predicate)
    // consume t = base+j (base<=344, j<=7 -> t<=351), prefetch t = base+j+8 <= 359
    constexpr int MAINC = ((TSTEPS - PF) / PF) * PF;  // 352 -> bases 0..344
    for (int base = 0; base < MAINC; base += PF) {
#pragma unroll
        for (int j = 0; j < PF; ++j) {
            const F3 fv = buf[j];
            buf[j] = f3[fofs]; fofs += BGRID;   // prefetch t+PF
            step(fv);
        }
    }
    // ring now holds t = MAINC .. MAINC+PF-1 (352..359); fofs at t=360
    // --- drain chunk: consume 352..359, prefetch 360..364 (predicate, once)
#pragma unroll
    for (int j = 0; j < PF; ++j) {
        const F3 fv = buf[j];
        if (j < TSTEPS - MAINC - PF) { buf[j] = f3[fofs]; fofs += BGRID; }
        step(fv);
    }
    // --- final tail: consume 360..364 from ring
#pragma unroll
    for (int j = 0; j < TSTEPS - MAINC - PF; ++j) {   // 5 steps
        step(buf[j]);
    }
}

extern "C" void kernel_launch(void* const* d_in, const int* in_sizes, int n_in,
                              void* d_out, int out_size, void* d_ws, size_t ws_size,
                              hipStream_t stream) {
    // inputs (fp32): 0 forcing, 1 parBETA, 2 parFC, 3 parK0, 4 parK1, 5 parK2,
    // 6 parLP, 7 parPERC, 8 parUZL, 9 parTT, 10 parCFMAX, 11 parCFR, 12 parCWH,
    // 13 parBETAET, 14 parC
    const float* forcing = (const float*)d_in[0];

    float* out_avg = (float*)d_out;                          // (T, B)
    float* out_q   = out_avg + (size_t)TSTEPS * BGRID;       // (T, B, NMUL)

    const int total = BGRID * NMUL;    // 80000
    const int block = 64;              // 1250 single-wave workgroups
    const int grid  = (total + block - 1) / block;
    hbv_fwd<<<grid, block, 0, stream>>>(forcing,
        (const float*)d_in[1], (const float*)d_in[2], (const float*)d_in[3],
        (const float*)d_in[4], (const float*)d_in[5], (const float*)d_in[6],
        (const float*)d_in[7], (const float*)d_in[8], (const float*)d_in[9],
        (const float*)d_in[10], (const float*)d_in[11], (const float*)d_in[12],
        (const float*)d_in[13], (const float*)d_in[14],
        out_avg, out_q);
}